// Round 3
// baseline (395.506 us; speedup 1.0000x reference)
//
#include <hip/hip_runtime.h>
#include <hip/hip_bf16.h>
#include <stdint.h>

#define M_NODES 100000
#define KF 256
#define NF 256
#define NRELS 3
#define NEDGES 300000
#define TOT_EDGES (NRELS * NEDGES)
#define TOTK (NRELS * M_NODES)          // 300000 segment keys (r, dst)
#define NB2 1172                         // ceil(TOTK/256)
#define KCAT (NRELS * KF)                // 768

typedef __attribute__((ext_vector_type(8))) short bf16x8;
typedef __attribute__((ext_vector_type(4))) float f32x4;

typedef const __attribute__((address_space(1))) unsigned int guint_t;
typedef __attribute__((address_space(3))) unsigned int luint_t;

__device__ __forceinline__ unsigned short f32_to_bf16(float f) {
    union { float f; uint32_t u; } c; c.f = f;
    uint32_t u = c.u;
    uint32_t r = (u + 0x7FFFu + ((u >> 16) & 1u)) >> 16;
    return (unsigned short)r;
}

// ---------------------------------------------------------------------------
// W [3][256k][256n] fp32  ->  Bt [256n][768kcat] bf16  (coalesced writes)
// ---------------------------------------------------------------------------
__global__ __launch_bounds__(256)
void k_wt(const float* __restrict__ w, unsigned short* __restrict__ Bt)
{
    int gid = blockIdx.x * 256 + threadIdx.x;     // 768*256 threads
    if (gid >= NF * KCAT) return;
    int n = gid / KCAT;
    int kc = gid - n * KCAT;                      // contiguous per-thread-run
    int r = kc >> 8, k = kc & 255;
    Bt[(size_t)n * KCAT + kc] = f32_to_bf16(w[((size_t)r * KF + k) * NF + n]);
}

// ---------------------------------------------------------------------------
// CSR build keyed by (r, dst) -> key = r*M + d
// ---------------------------------------------------------------------------
__global__ __launch_bounds__(256)
void k_hist(const int* __restrict__ dst, int* __restrict__ counts)
{
    int e = blockIdx.x * 256 + threadIdx.x;
    if (e >= TOT_EDGES) return;
    int r = e / NEDGES;
    atomicAdd(&counts[r * M_NODES + dst[e]], 1);
}

__global__ __launch_bounds__(256)
void k_blocksum(const int* __restrict__ counts, int* __restrict__ bsum)
{
    __shared__ int s[256];
    int i = blockIdx.x * 256 + threadIdx.x;
    s[threadIdx.x] = (i < TOTK) ? counts[i] : 0;
    __syncthreads();
    for (int st = 128; st > 0; st >>= 1) {
        if (threadIdx.x < st) s[threadIdx.x] += s[threadIdx.x + st];
        __syncthreads();
    }
    if (threadIdx.x == 0) bsum[blockIdx.x] = s[0];
}

// single-block scan of NB2 block sums
__global__ __launch_bounds__(256)
void k_scan1(const int* __restrict__ bsum, int* __restrict__ bpre)
{
    __shared__ int tot[256];
    int t = threadIdx.x;
    int base = t * 5;                    // 5*256 = 1280 >= 1172
    int v[5]; int s = 0;
#pragma unroll
    for (int i = 0; i < 5; ++i) {
        int idx = base + i;
        v[i] = (idx < NB2) ? bsum[idx] : 0;
        s += v[i];
    }
    tot[t] = s;
    __syncthreads();
    if (t == 0) {
        int a = 0;
        for (int i = 0; i < 256; ++i) { int tmp = tot[i]; tot[i] = a; a += tmp; }
    }
    __syncthreads();
    int a = tot[t];
#pragma unroll
    for (int i = 0; i < 5; ++i) {
        int idx = base + i;
        if (idx < NB2) bpre[idx] = a;
        a += v[i];
    }
}

__global__ __launch_bounds__(256)
void k_offsets(const int* __restrict__ counts, const int* __restrict__ bpre,
               int* __restrict__ off, int* __restrict__ cur)
{
    __shared__ int s[257];
    int i = blockIdx.x * 256 + threadIdx.x;
    int v = (i < TOTK) ? counts[i] : 0;
    if (threadIdx.x == 0) s[0] = 0;
    s[threadIdx.x + 1] = v;
    __syncthreads();
    if (threadIdx.x == 0) {
        int acc = 0;
        for (int j = 0; j < 256; ++j) { int t = s[j + 1]; s[j + 1] = acc; acc += t; }
    }
    __syncthreads();
    if (i < TOTK) {
        int o = bpre[blockIdx.x] + s[threadIdx.x + 1];
        off[i] = o;
        cur[i] = o;
    }
}

__global__ __launch_bounds__(256)
void k_scatter(const int* __restrict__ src, const int* __restrict__ dst,
               int* __restrict__ cur, int* __restrict__ perm)
{
    int e = blockIdx.x * 256 + threadIdx.x;
    if (e >= TOT_EDGES) return;
    int r = e / NEDGES;
    int key = r * M_NODES + dst[e];
    int pos = atomicAdd(&cur[key], 1);
    perm[pos] = src[e];
}

// ---------------------------------------------------------------------------
// Gather-sum of raw x rows (fp32) per (r,dst) key -> xagg bf16 [3*M][256]
// One wave per key; float4/lane coalesced row loads; fp32 accumulate.
// ---------------------------------------------------------------------------
__global__ __launch_bounds__(256)
void k_gather(const float* __restrict__ x, const int* __restrict__ off,
              const int* __restrict__ counts, const int* __restrict__ perm,
              unsigned short* __restrict__ xagg)
{
    int key = (blockIdx.x * 256 + threadIdx.x) >> 6;
    if (key >= TOTK) return;
    int lane = threadIdx.x & 63;
    int start = off[key];
    int n = counts[key];

    float a0 = 0.f, a1 = 0.f, a2 = 0.f, a3 = 0.f;
    for (int j = 0; j < n; ++j) {
        int s = perm[start + j];
        float4 v = *(const float4*)(x + (size_t)s * KF + lane * 4);
        a0 += v.x; a1 += v.y; a2 += v.z; a3 += v.w;
    }
    ushort4 o;
    o.x = f32_to_bf16(a0);
    o.y = f32_to_bf16(a1);
    o.z = f32_to_bf16(a2);
    o.w = f32_to_bf16(a3);
    *(ushort4*)(xagg + (size_t)key * KF + lane * 4) = o;
}

// ---------------------------------------------------------------------------
// Fused GEMM + relu: out[d] = relu( sum_r xagg[r*M+d] @ W_r )
// M=100000, N=256, K=768 (kt = r*8 + kk, BK=32).
// 512 threads = 8 waves (2 wr x 4 wc), each wave 64x64.
// A: global_load_lds w16, double-buffered, XOR-swizzled (src-side) LDS.
// B: fragments loaded directly from L2-resident Bt (no LDS).
// ---------------------------------------------------------------------------
__global__ __launch_bounds__(512, 2)
void gemm_fused(const unsigned short* __restrict__ xagg,
                const unsigned short* __restrict__ Bt,
                float* __restrict__ out)
{
    const int m0 = blockIdx.x * 128;
    const int t = threadIdx.x;
    const int lane = t & 63;
    const int wid = t >> 6;
    const int wr = wid >> 2, wc = wid & 3;
    const int l16 = lane & 15, lg = lane >> 4;

    __shared__ short As[2][128 * 32];   // linear layout; swizzle applied on src+read

    f32x4 acc[4][4] = {};

    // --- staging geometry: wave wid stages local rows [wid*16, wid*16+16)
    // lane l -> LDS slot (row = wid*16 + (l>>2), chunk c = l&3); 16B per lane.
    // slot (row,c) must hold global chunk c ^ s(row), s(row) = (row>>1)&3.
    // For this lane: s = (l>>3)&3 (wid*16 contributes 0 mod 4).
    const int srow = wid * 16 + (lane >> 2);
    int sgm = m0 + srow;
    if (sgm >= M_NODES) sgm = M_NODES - 1;       // clamp: affects only unwritten rows
    const int cg = (lane & 3) ^ ((lane >> 3) & 3);
    const size_t srow_base = (size_t)sgm * KF + cg * 8;   // + r*M*KF + kk*32 at stage

    // --- B fragment bases: Bt[(wc*64 + j*16 + l16)][kt*32 + lg*8]
    const unsigned short* bbase = Bt + (size_t)(wc * 64 + l16) * KCAT + lg * 8;

    // --- A fragment read swizzle: byte addr = row*64 + ((lg ^ ((l16>>1)&3))*16)
    const int asw = (lg ^ ((l16 >> 1) & 3)) * 8;          // in shorts

#define STAGE(buf, kt_) do {                                                   \
        int r_ = (kt_) >> 3, kk_ = (kt_) & 7;                                  \
        const unsigned short* gsrc = xagg +                                    \
            ((size_t)r_ * M_NODES * KF + srow_base + kk_ * 32);                \
        __builtin_amdgcn_global_load_lds((guint_t*)gsrc,                       \
            (luint_t*)((char*)&As[buf][0] + wid * 1024), 16, 0, 0);            \
    } while (0)

    STAGE(0, 0);
    __syncthreads();

    for (int kt = 0; kt < 24; ++kt) {
        int buf = kt & 1;
        if (kt < 23) STAGE(buf ^ 1, kt + 1);

        bf16x8 b[4];
#pragma unroll
        for (int j = 0; j < 4; ++j)
            b[j] = *(const bf16x8*)(bbase + (size_t)j * 16 * KCAT + kt * 32);

        bf16x8 a[4];
#pragma unroll
        for (int i = 0; i < 4; ++i) {
            int arow = wr * 64 + i * 16 + l16;
            a[i] = *(bf16x8*)(&As[buf][0] + arow * 32 + asw);
        }

#pragma unroll
        for (int i = 0; i < 4; ++i)
#pragma unroll
            for (int j = 0; j < 4; ++j)
                acc[i][j] = __builtin_amdgcn_mfma_f32_16x16x32_bf16(
                    a[i], b[j], acc[i][j], 0, 0, 0);

        __syncthreads();   // drains vmcnt (stage kt+1 done) + protects buf reuse
    }
#undef STAGE

    // --- epilogue: relu + store
#pragma unroll
    for (int i = 0; i < 4; ++i) {
        int row_base = m0 + wr * 64 + i * 16 + lg * 4;
#pragma unroll
        for (int q = 0; q < 4; ++q) {
            int row = row_base + q;
            if (row < M_NODES) {
#pragma unroll
                for (int j = 0; j < 4; ++j) {
                    int col = wc * 64 + j * 16 + l16;
                    out[(size_t)row * NF + col] = fmaxf(acc[i][j][q], 0.f);
                }
            }
        }
    }
}

extern "C" void kernel_launch(void* const* d_in, const int* in_sizes, int n_in,
                              void* d_out, int out_size, void* d_ws, size_t ws_size,
                              hipStream_t stream)
{
    const float* x   = (const float*)d_in[0];
    const float* w   = (const float*)d_in[1];
    const int*   src = (const int*)d_in[2];
    const int*   dst = (const int*)d_in[3];
    float* out = (float*)d_out;

    // workspace layout (~161.2 MB)
    char* ws = (char*)d_ws;
    unsigned short* xagg = (unsigned short*)ws;               // 153,600,000
    size_t o = (size_t)TOTK * KF * sizeof(unsigned short);
    int* counts = (int*)(ws + o);  o += (size_t)TOTK * 4;     // 1.2 MB
    int* off    = (int*)(ws + o);  o += (size_t)TOTK * 4;
    int* cur    = (int*)(ws + o);  o += (size_t)TOTK * 4;
    int* bsum   = (int*)(ws + o);  o += 8192;
    int* bpre   = (int*)(ws + o);  o += 8192;
    int* perm   = (int*)(ws + o);  o += (size_t)TOT_EDGES * 4;
    unsigned short* Bt = (unsigned short*)(ws + o); o += (size_t)NF * KCAT * 2;

    hipMemsetAsync(counts, 0, (size_t)TOTK * 4, stream);

    k_wt<<<(NF * KCAT + 255) / 256, 256, 0, stream>>>(w, Bt);

    int eb = (TOT_EDGES + 255) / 256;
    k_hist<<<eb, 256, 0, stream>>>(dst, counts);
    k_blocksum<<<NB2, 256, 0, stream>>>(counts, bsum);
    k_scan1<<<1, 256, 0, stream>>>(bsum, bpre);
    k_offsets<<<NB2, 256, 0, stream>>>(counts, bpre, off, cur);
    k_scatter<<<eb, 256, 0, stream>>>(src, dst, cur, perm);

    int gb = (TOTK * 64 + 255) / 256;    // one wave per key
    k_gather<<<gb, 256, 0, stream>>>(x, off, counts, perm, xagg);

    gemm_fused<<<(M_NODES + 127) / 128, 512, 0, stream>>>(xagg, Bt, out);
}